// Round 7
// baseline (433.214 us; speedup 1.0000x reference)
//
#include <hip/hip_runtime.h>
#include <stdint.h>

#define Bb 8
#define Cc 256
#define Nn 2304
#define KSPLIT 3
#define TPS 24   // 32-key tiles per split: 2304/32/3
#define L2E 1.44269504088896f

typedef unsigned short u16;
typedef _Float16 h16;
typedef h16  h16x8 __attribute__((ext_vector_type(8)));
typedef u16  u16x8 __attribute__((ext_vector_type(8)));
typedef float f32x4 __attribute__((ext_vector_type(4)));

static __device__ __forceinline__ u16 f2h(float f) {
  return __builtin_bit_cast(u16, (h16)f);
}
static __device__ __forceinline__ h16x8 ash(u16x8 v) {
  return __builtin_bit_cast(h16x8, v);
}
static __device__ __forceinline__ f32x4 mfma16(u16x8 a, u16x8 b, f32x4 c) {
  return __builtin_amdgcn_mfma_f32_16x16x32_f16(ash(a), ash(b), c, 0, 0, 0);
}

// DPP row_ror reductions over 16 lanes (VALU pipe)
template <int CTRL>
static __device__ __forceinline__ float dppmov(float x) {
  return __builtin_bit_cast(float,
      __builtin_amdgcn_mov_dpp(__builtin_bit_cast(int, x), CTRL, 0xF, 0xF, true));
}
static __device__ __forceinline__ float rowmax16(float x) {
  x = fmaxf(x, dppmov<0x121>(x));
  x = fmaxf(x, dppmov<0x122>(x));
  x = fmaxf(x, dppmov<0x124>(x));
  x = fmaxf(x, dppmov<0x128>(x));
  return x;
}
static __device__ __forceinline__ float rowsum16(float x) {
  x += dppmov<0x121>(x);
  x += dppmov<0x122>(x);
  x += dppmov<0x124>(x);
  x += dppmov<0x128>(x);
  return x;
}

// ---------------------------------------------------------------------------
// Prep: Wq,Wk,Wv fp32 [C][C] -> fp16 Wf [3][C*C].
// ---------------------------------------------------------------------------
__global__ void prep_kernel(const float* __restrict__ Wq,
                            const float* __restrict__ Wk,
                            const float* __restrict__ Wv,
                            u16* __restrict__ Wf)
{
  const int tid = blockIdx.x * 256 + threadIdx.x;
  const int m   = tid >> 13;
  const int off = (tid & 8191) * 8;
  const float* src = (m == 0) ? Wq : (m == 1) ? Wk : Wv;
  const f32x4 a = *(const f32x4*)(src + off);
  const f32x4 c = *(const f32x4*)(src + off + 4);
  u16x8 o;
#pragma unroll
  for (int j = 0; j < 4; ++j) { o[j] = f2h(a[j]); o[j + 4] = f2h(c[j]); }
  *(u16x8*)(Wf + (size_t)m * 65536 + off) = o;
}

// ---------------------------------------------------------------------------
// Projection v7. launch_bounds(256,2) — VGPR cap 256, no spill (the prior
// (256,3)=~170 cap is the suspected 130-us pathology). Input tile f32x4-
// loaded and transposed through LDS (pad-264 rows, <=2-way). Epilogues
// transpose through LDS for coalesced u16x8 global stores.
// z=0: Q [B][N][C], z=1: K [B][N][C], z=2: V^T [B][C][N]. grid (8,36,3).
// ---------------------------------------------------------------------------
#define SA_SZ 18432   // union: input 64x264 u16 (16896) / z2-epi 256x72 (18432)
__global__ __launch_bounds__(256, 2) void proj_kernel(
    const float* __restrict__ x, const float* __restrict__ y,
    const u16* __restrict__ Wf,
    const float* __restrict__ bq, const float* __restrict__ bk,
    const float* __restrict__ bv,
    u16* __restrict__ Qf, u16* __restrict__ Kf, u16* __restrict__ Vf)
{
  __shared__ u16 sA[SA_SZ];
  __shared__ u16 sW[32 * 256];
  const int t    = threadIdx.x;
  const int b    = blockIdx.x;
  const int q0   = blockIdx.y * 64;
  const int z    = blockIdx.z;
  const int lane = t & 63;
  const int w    = t >> 6;
  const int quad = lane >> 4;
  const int l15  = lane & 15;
  const u16* WZ = Wf + (size_t)z * 65536;

  // ---- stage input tile: f32x4 token-quad loads -> [tok][c] u16, pad 264 ----
  {
    const float* src = (z == 0) ? x : y;
    const float* pc = src + ((size_t)b * Cc + t) * Nn + q0;
#pragma unroll 4
    for (int it = 0; it < 16; ++it) {
      const f32x4 v4 = *(const f32x4*)(pc + it * 4);
#pragma unroll
      for (int j = 0; j < 4; ++j)
        sA[(it * 4 + j) * 264 + t] = f2h(v4[j]);
    }
  }
  __syncthreads();

  // ---- token fragments from LDS (A-operand for z<2, B-operand for z==2) ----
  u16x8 af[8];
  {
    const int trow = w * 16 + l15;
#pragma unroll
    for (int kc = 0; kc < 8; ++kc)
      af[kc] = *(const u16x8*)(sA + trow * 264 + kc * 32 + quad * 8);
  }

  f32x4 acc[16];
#pragma unroll
  for (int i = 0; i < 16; ++i) acc[i] = (f32x4){0.f, 0.f, 0.f, 0.f};

  // ---- 8 rounds of 32 c_out rows; W staged coalesced, swizzled reads ----
#pragma unroll 1
  for (int rg = 0; rg < 8; ++rg) {
    __syncthreads();
#pragma unroll
    for (int it = 0; it < 4; ++it) {
      const int id = it * 256 + t;
      const int row = id >> 5, gch = id & 31;
      const u16x8 v = *(const u16x8*)(WZ + (size_t)(rg * 32 + row) * 256 + gch * 8);
      *(u16x8*)(sW + row * 256 + ((gch ^ (row & 7)) << 3)) = v;
    }
    __syncthreads();
    if (z < 2) {
#pragma unroll
      for (int cbl = 0; cbl < 2; ++cbl) {
        const int rl = cbl * 16 + l15;
        f32x4 a = acc[rg * 2 + cbl];
#pragma unroll
        for (int kc = 0; kc < 8; ++kc) {
          const u16x8 bf = *(const u16x8*)(sW + rl * 256 + (((kc * 4 + quad) ^ (rl & 7)) << 3));
          a = mfma16(af[kc], bf, a);
        }
        acc[rg * 2 + cbl] = a;
      }
    } else {
#pragma unroll
      for (int mt = 0; mt < 2; ++mt) {
        const int rl = mt * 16 + l15;
        f32x4 a = acc[rg * 2 + mt];
#pragma unroll
        for (int kc = 0; kc < 8; ++kc) {
          const u16x8 wfr = *(const u16x8*)(sW + rl * 256 + (((kc * 4 + quad) ^ (rl & 7)) << 3));
          a = mfma16(wfr, af[kc], a);
        }
        acc[rg * 2 + mt] = a;
      }
    }
  }

  // ---- epilogue: transpose through sA, coalesced u16x8 stores ----
  if (z < 2) {
    const float* bias = (z == 0) ? bq : bk;
    u16* O = (z == 0) ? Qf : Kf;
#pragma unroll
    for (int i = 0; i < 16; ++i) {
      const int co = i * 16 + l15;
      const float bs = bias[co];
      const int chunk = co >> 3;
      const int wi = co & 7;
#pragma unroll
      for (int r = 0; r < 4; ++r) {
        const int tok = w * 16 + quad * 4 + r;
        sA[tok * 264 + ((chunk ^ (tok & 3)) << 3) + wi] = f2h(acc[i][r] + bs);
      }
    }
    __syncthreads();
#pragma unroll
    for (int it = 0; it < 8; ++it) {
      const int tok = w * 16 + (lane >> 2);
      const int ch = (lane & 3) + 4 * it;
      const u16x8 v = *(const u16x8*)(sA + tok * 264 + ((ch ^ (tok & 3)) << 3));
      *(u16x8*)(O + ((size_t)b * Nn + q0 + tok) * 256 + ch * 8) = v;
    }
  } else {
#pragma unroll
    for (int i = 0; i < 16; ++i) {
#pragma unroll
      for (int r = 0; r < 4; ++r) {
        const int co = i * 16 + quad * 4 + r;
        sA[co * 72 + w * 16 + l15] = f2h(acc[i][r] + bv[co]);
      }
    }
    __syncthreads();
#pragma unroll
    for (int it = 0; it < 8; ++it) {
      const int id = it * 256 + t;
      const int co = id >> 3, tc = id & 7;
      const u16x8 v = *(const u16x8*)(sA + co * 72 + tc * 8);
      *(u16x8*)(Vf + ((size_t)b * Cc + co) * Nn + q0 + tc * 8) = v;
    }
  }
}

// ---------------------------------------------------------------------------
// Flash attention v7: 32 queries/wave (2-wave blocks, 64 q/block) — K/V
// LDS fragment reads per query HALVED vs 16q waves. KSPLIT=3, grid
// (8,36,3)=864 blocks. 32-key tiles staged by coalesced vector loads +
// swizzled ds_writes (stall overlapped by ~3 co-resident blocks).
// LDS 36 KB: sK[32][256], sV[256][32], sP 2x(32x32).
// ---------------------------------------------------------------------------
__global__ __launch_bounds__(128, 2) void attn_kernel(
    const u16* __restrict__ Qf, const u16* __restrict__ Kf,
    const u16* __restrict__ Vf, float* __restrict__ Opart,
    float* __restrict__ Ml)
{
  __shared__ u16 sK[32 * 256];
  __shared__ u16 sV[256 * 32];
  __shared__ u16 sP[2 * 1024];
  const int t    = threadIdx.x;     // 0..127
  const int b    = blockIdx.x;
  const int q0   = blockIdx.y * 64;
  const int sp   = blockIdx.z;
  const int lane = t & 63;
  const int w    = t >> 6;          // 0..1
  const int quad = lane >> 4;
  const int l15  = lane & 15;

  // Q A-frags: 2 groups of 16 queries per wave
  u16x8 qf[2][8];
#pragma unroll
  for (int qg = 0; qg < 2; ++qg) {
    const size_t qrow = ((size_t)b * Nn + q0 + w * 32 + qg * 16 + l15) * Cc;
#pragma unroll
    for (int kc = 0; kc < 8; ++kc)
      qf[qg][kc] = *(const u16x8*)(Qf + qrow + kc * 32 + quad * 8);
  }

  f32x4 o0[16], o1[16];
#pragma unroll
  for (int i = 0; i < 16; ++i) {
    o0[i] = (f32x4){0.f, 0.f, 0.f, 0.f};
    o1[i] = (f32x4){0.f, 0.f, 0.f, 0.f};
  }
  float mrow[2][4], lrow[2][4];
#pragma unroll
  for (int qg = 0; qg < 2; ++qg)
#pragma unroll
    for (int r = 0; r < 4; ++r) { mrow[qg][r] = -3e38f; lrow[qg][r] = 0.f; }

  const u16* Kb = Kf + (size_t)b * Nn * Cc;
  const u16* Vb = Vf + (size_t)b * Cc * Nn;
  const int gl = (l15 & 3) ^ ((l15 >> 2) & 3);
  u16* Pw = sP + w * 1024;

#pragma unroll 1
  for (int kb = 0; kb < TPS; ++kb) {
    __syncthreads();   // prev tile's LDS reads done
    const size_t kg0 = ((size_t)sp * TPS + kb) * 32;
    // ---- stage K [32][256] + V^T [256][32] (coalesced loads, swizzled) ----
#pragma unroll
    for (int it = 0; it < 8; ++it) {
      const int id = it * 128 + t;
      const int row = id >> 5, ch = id & 31;
      const u16x8 kv = *(const u16x8*)(Kb + (kg0 + row) * Cc + ch * 8);
      *(u16x8*)(sK + row * 256 + ((ch ^ (row & 7)) << 3)) = kv;
      const int c = id >> 2, p = id & 3;
      const u16x8 vv = *(const u16x8*)(Vb + (size_t)c * Nn + kg0 + p * 8);
      *(u16x8*)(sV + c * 32 + ((p ^ ((c >> 1) & 3)) << 3)) = vv;
    }
    __syncthreads();

    // ---- S = Q K^T : 2 q-groups x 2 key-halves, K-frags shared ----
    f32x4 s00 = {0.f,0.f,0.f,0.f}, s01 = s00, s10 = s00, s11 = s00;
#pragma unroll
    for (int kc = 0; kc < 8; ++kc) {
      const int ch = ((kc * 4 + quad) ^ (l15 & 7)) << 3;
      const u16x8 k0 = *(const u16x8*)(sK + l15 * 256 + ch);
      const u16x8 k1 = *(const u16x8*)(sK + (16 + l15) * 256 + ch);
      s00 = mfma16(qf[0][kc], k0, s00);
      s01 = mfma16(qf[0][kc], k1, s01);
      s10 = mfma16(qf[1][kc], k0, s10);
      s11 = mfma16(qf[1][kc], k1, s11);
    }

    // ---- online softmax (8 independent DPP chains) ----
    float m0[2][4], al[2][4], sums[2][4];
#pragma unroll
    for (int r = 0; r < 4; ++r) {
      m0[0][r] = fmaxf(s00[r], s01[r]);
      m0[1][r] = fmaxf(s10[r], s11[r]);
    }
#pragma unroll
    for (int qg = 0; qg < 2; ++qg)
#pragma unroll
      for (int r = 0; r < 4; ++r) m0[qg][r] = rowmax16(m0[qg][r]);
#pragma unroll
    for (int r = 0; r < 4; ++r) {
      {
        const float mn = fmaxf(mrow[0][r], m0[0][r]);
        al[0][r] = exp2f((mrow[0][r] - mn) * L2E);
        mrow[0][r] = mn;
        const float p0 = exp2f((s00[r] - mn) * L2E);
        const float p1 = exp2f((s01[r] - mn) * L2E);
        s00[r] = p0; s01[r] = p1; sums[0][r] = p0 + p1;
      }
      {
        const float mn = fmaxf(mrow[1][r], m0[1][r]);
        al[1][r] = exp2f((mrow[1][r] - mn) * L2E);
        mrow[1][r] = mn;
        const float p0 = exp2f((s10[r] - mn) * L2E);
        const float p1 = exp2f((s11[r] - mn) * L2E);
        s10[r] = p0; s11[r] = p1; sums[1][r] = p0 + p1;
      }
    }
#pragma unroll
    for (int qg = 0; qg < 2; ++qg)
#pragma unroll
      for (int r = 0; r < 4; ++r) sums[qg][r] = rowsum16(sums[qg][r]);
#pragma unroll
    for (int qg = 0; qg < 2; ++qg)
#pragma unroll
      for (int r = 0; r < 4; ++r)
        lrow[qg][r] = lrow[qg][r] * al[qg][r] + sums[qg][r];

    bool need = false;
#pragma unroll
    for (int qg = 0; qg < 2; ++qg)
#pragma unroll
      for (int r = 0; r < 4; ++r) need |= (al[qg][r] < 1.f);
    if (__any(need)) {
#pragma unroll
      for (int i = 0; i < 16; ++i) {
#pragma unroll
        for (int r = 0; r < 4; ++r) {
          o0[i][r] *= al[0][r];
          o1[i][r] *= al[1][r];
        }
      }
    }

    // ---- P: C/D -> sP (wave-local, per q-group) -> A layout ----
    {
      const int kch0 = l15 >> 3;
#pragma unroll
      for (int r = 0; r < 4; ++r) {
        const int row = quad * 4 + r;
        const int gx = r ^ quad;
        u16* P0 = Pw;
        u16* P1 = Pw + 512;
        P0[row * 32 + ((kch0 ^ gx) << 3) + (l15 & 7)] = f2h(s00[r]);
        P0[row * 32 + (((2 + kch0) ^ gx) << 3) + (l15 & 7)] = f2h(s01[r]);
        P1[row * 32 + ((kch0 ^ gx) << 3) + (l15 & 7)] = f2h(s10[r]);
        P1[row * 32 + (((2 + kch0) ^ gx) << 3) + (l15 & 7)] = f2h(s11[r]);
      }
    }
    __builtin_amdgcn_s_waitcnt(0xC07F);  // lgkmcnt(0)
    const u16x8 pf0 = *(const u16x8*)(Pw + l15 * 32 + ((quad ^ gl) << 3));
    const u16x8 pf1 = *(const u16x8*)(Pw + 512 + l15 * 32 + ((quad ^ gl) << 3));

    // ---- O += P V : V-frag read once, serves both q-groups ----
#pragma unroll
    for (int cb2 = 0; cb2 < 16; ++cb2) {
      const int c = cb2 * 16 + l15;
      const u16x8 vf = *(const u16x8*)(sV + c * 32 + ((quad ^ ((c >> 1) & 3)) << 3));
      o0[cb2] = mfma16(pf0, vf, o0[cb2]);
      o1[cb2] = mfma16(pf1, vf, o1[cb2]);
    }
  }

  // ---- epilogue: unnormalized partials ----
  float* Ob = Opart + ((size_t)sp * Bb + b) * (size_t)Cc * Nn;
#pragma unroll
  for (int cb2 = 0; cb2 < 16; ++cb2) {
    const int c = cb2 * 16 + l15;
    float* base = Ob + (size_t)c * Nn + q0 + w * 32 + quad * 4;
    *(f32x4*)base = o0[cb2];
    *(f32x4*)(base + 16) = o1[cb2];
  }
  if (l15 == 0) {
    float* mlb = Ml + ((size_t)sp * Bb + b) * (size_t)Nn * 2;
#pragma unroll
    for (int qg = 0; qg < 2; ++qg)
#pragma unroll
      for (int r = 0; r < 4; ++r) {
        const int n = q0 + w * 32 + qg * 16 + quad * 4 + r;
        mlb[n * 2]     = mrow[qg][r];
        mlb[n * 2 + 1] = lrow[qg][r];
      }
  }
}

// ---------------------------------------------------------------------------
// Merge the 3 K-split partials.
// ---------------------------------------------------------------------------
__global__ void merge_kernel(const float* __restrict__ Opart,
                             const float* __restrict__ Ml,
                             float* __restrict__ out)
{
  const int idx = blockIdx.x * 256 + threadIdx.x;  // Bb*Cc*576
  const int n4 = idx % 576;
  const int bc = idx / 576;
  const int b  = bc >> 8;
  const size_t NCt = (size_t)Bb * Cc * Nn;
  const size_t ooff = (size_t)bc * Nn + n4 * 4;
  f32x4 os[KSPLIT];
  float mm[KSPLIT][4], ll[KSPLIT][4];
#pragma unroll
  for (int s = 0; s < KSPLIT; ++s) {
    os[s] = *(const f32x4*)(Opart + ooff + (size_t)s * NCt);
    const float* mlb = Ml + ((size_t)s * Bb + b) * (size_t)Nn * 2;
#pragma unroll
    for (int j = 0; j < 4; ++j) {
      mm[s][j] = mlb[(n4 * 4 + j) * 2];
      ll[s][j] = mlb[(n4 * 4 + j) * 2 + 1];
    }
  }
  f32x4 r;
#pragma unroll
  for (int j = 0; j < 4; ++j) {
    float m = mm[0][j];
#pragma unroll
    for (int s = 1; s < KSPLIT; ++s) m = fmaxf(m, mm[s][j]);
    float num = 0.f, den = 0.f;
#pragma unroll
    for (int s = 0; s < KSPLIT; ++s) {
      const float wgt = exp2f((mm[s][j] - m) * L2E);
      num += os[s][j] * wgt;
      den += ll[s][j] * wgt;
    }
    r[j] = num / den;
  }
  *(f32x4*)(out + ooff) = r;
}

extern "C" void kernel_launch(void* const* d_in, const int* in_sizes, int n_in,
                              void* d_out, int out_size, void* d_ws, size_t ws_size,
                              hipStream_t stream) {
  const float* x  = (const float*)d_in[0];
  const float* y  = (const float*)d_in[1];
  const float* Wq = (const float*)d_in[2];
  const float* bq = (const float*)d_in[3];
  const float* Wk = (const float*)d_in[4];
  const float* bk = (const float*)d_in[5];
  const float* Wv = (const float*)d_in[6];
  const float* bv = (const float*)d_in[7];
  float* out = (float*)d_out;

  const size_t NC = (size_t)Bb * Nn * Cc;   // 4,718,592
  u16* Qf = (u16*)d_ws;
  u16* Kf = Qf + NC;
  u16* Vf = Kf + NC;
  u16* Wf = Vf + NC;
  float* Opart = (float*)(Wf + 3 * 65536);       // KSPLIT*NC f32
  float* Ml    = Opart + (size_t)KSPLIT * NC;    // KSPLIT*Bb*Nn*2 f32

  hipLaunchKernelGGL(prep_kernel, dim3(96), dim3(256), 0, stream,
                     Wq, Wk, Wv, Wf);
  hipLaunchKernelGGL(proj_kernel, dim3(Bb, 36, 3), dim3(256), 0, stream,
                     x, y, Wf, bq, bk, bv, Qf, Kf, Vf);
  hipLaunchKernelGGL(attn_kernel, dim3(Bb, 36, KSPLIT), dim3(128), 0, stream,
                     Qf, Kf, Vf, Opart, Ml);
  hipLaunchKernelGGL(merge_kernel, dim3(4608), dim3(256), 0, stream,
                     Opart, Ml, out);
}